// Round 22
// baseline (237.983 us; speedup 1.0000x reference)
//
#include <hip/hip_runtime.h>
#include <hip/hip_bf16.h>

#define B_N 32
#define T_N 512
#define D_N 512
#define H_N 512
#define M_N (B_N * T_N)   // 16384

typedef __attribute__((ext_vector_type(8))) short bf16x8;   // generic 16B
typedef __attribute__((ext_vector_type(4))) float f32x4;

__device__ __forceinline__ unsigned short f2bf(float f) {
  unsigned u = __float_as_uint(f);
  u += 0x7FFFu + ((u >> 16) & 1u);   // RTNE
  return (unsigned short)(u >> 16);
}
__device__ __forceinline__ unsigned short f2h(float f) {
  _Float16 h = (_Float16)f;
  return *(unsigned short*)&h;
}
__device__ __forceinline__ float h2f(unsigned short u) {
  _Float16 h = *(_Float16*)&u;
  return (float)h;
}

#define GLOAD16(g, l) __builtin_amdgcn_global_load_lds( \
    (const __attribute__((address_space(1))) void*)(g), \
    (__attribute__((address_space(3))) void*)(l), 16, 0, 0)

// ---------------------------------------------------------------------------
// prep: blocks [0,768) transpose+convert W -> Wt[id][n][k] bf16;
// blocks [768,2816) convert x f32 -> bf16; blocks [2816,2848) zero S1/S2.
// ---------------------------------------------------------------------------
__global__ void prep_kernel(const float* __restrict__ x,
                            const float* __restrict__ W0,
                            const float* __restrict__ W1,
                            const float* __restrict__ W2,
                            unsigned short* __restrict__ xb,
                            unsigned short* __restrict__ Wt,
                            float* __restrict__ S) {
  int blk = blockIdx.x;
  int tid = threadIdx.x;
  if (blk < 768) {
    __shared__ float tile[32][33];
    int id = blk >> 8;
    int t = blk & 255;
    int kr = (t >> 4) << 5;
    int nc = (t & 15) << 5;
    const float* W = (id == 0) ? W0 : (id == 1) ? W1 : W2;
    unsigned short* Wo = Wt + (size_t)id * (D_N * H_N);
    int tx = tid & 31, ty0 = tid >> 5;
    for (int ty = ty0; ty < 32; ty += 8)
      tile[ty][tx] = W[(size_t)(kr + ty) * H_N + nc + tx];
    __syncthreads();
    for (int ty = ty0; ty < 32; ty += 8)
      Wo[(size_t)(nc + ty) * D_N + kr + tx] = f2bf(tile[tx][ty]);
  } else if (blk < 2816) {
    int b = blk - 768;
    const float4* xv = (const float4*)x;
#pragma unroll
    for (int u = 0; u < 4; ++u) {
      int i = b * 1024 + u * 256 + tid;
      float4 v = xv[i];
      ushort4 o;
      o.x = f2bf(v.x); o.y = f2bf(v.y); o.z = f2bf(v.z); o.w = f2bf(v.w);
      ((ushort4*)xb)[i] = o;
    }
  } else {
    // zero S1+S2 (contiguous 128KB = 8192 float4)
    ((float4*)S)[(blk - 2816) * 256 + tid] = (float4){0.f, 0.f, 0.f, 0.f};
  }
}

// ---------------------------------------------------------------------------
// gemm3 v22: 64x128 WAVE-TILES (acc[4][8] = 128 AGPR), block = 4 waves =
// 128x256 tile, BK=64, 8 K-steps, single 48KB LDS buffer (A 16KB @0,
// B 32KB @16384), plain __syncthreads.
// Why: five structurally distinct configs (1/2/4 blocks/CU, 8/16 steps,
// 2x staging-volume delta) all landed at 43+-0.5us; the invariant is
// per-wave LDS-read traffic (30.8 b128/MFLOP at 64x64 tiles).  64x128
// cuts it 25% (22.9/MFLOP).  Regs ~188/wave -> 2 waves/SIMD (<=256
// quantum); NO launch_bounds (v4/v5 spill lesson).
// All fragment/swizzle math is the verified pattern, widened to nt=8 and
// B rows 0..255 (same phys-slot = s^(row&7), 128B rows; inverse folded
// into per-lane GLOBAL source, rule 21).  Epilogue verified v10.
// ---------------------------------------------------------------------------
__global__ void gemm3(
    const unsigned short* __restrict__ xb,
    const unsigned short* __restrict__ Wt,
    const float* __restrict__ bDu,
    const float* __restrict__ bDr1,
    const float* __restrict__ bDr2,
    unsigned short* __restrict__ uP,
    unsigned short* __restrict__ e1P,
    unsigned short* __restrict__ e2P,
    float* __restrict__ S1,
    float* __restrict__ S2) {
  __shared__ __align__(16) char smem[49152];   // A @0 (16KB), B @16384 (32KB)

  // chunked XCD swizzle (nwg=768 = 8*96): XCD k gets wg [k*96, k*96+96)
  const int wg = (blockIdx.x & 7) * 96 + (blockIdx.x >> 3);
  const int bx = wg / 6;            // 0..127  (M tile)
  const int rzy = wg - bx * 6;
  const int id = rzy >> 1;          // 0..2
  const int by = rzy & 1;           // 0..1    (N half)

  const int tid = threadIdx.x;      // 0..255
  const int lane = tid & 63;
  const int wv = tid >> 6;          // 0..3
  const int wr = wv >> 1;           // wave row (0..1)  -> 64-row slab
  const int wc = wv & 1;            // wave col (0..1)  -> 128-col slab
  const int g = lane >> 4;          // 0..3
  const int c16 = lane & 15;

  const int m0 = bx * 128;
  const int n0 = by * 256;
  const unsigned short* Wp = Wt + (size_t)id * (D_N * H_N);

  f32x4 acc[4][8];
#pragma unroll
  for (int mt = 0; mt < 4; ++mt)
#pragma unroll
    for (int nt = 0; nt < 8; ++nt)
      acc[mt][nt] = (f32x4){0.f, 0.f, 0.f, 0.f};

  // staging: chunk c -> row c>>3, phys slot c&7; logical = phys^(row&7).
  // A: 1024 chunks (128 rows), thread does i=0..3 (row = i*32 + tid>>3);
  // B: 2048 chunks (256 rows), thread does i=0..7.
  const int rowoff = tid >> 3;                         // 0..31
  const int lsl = ((tid & 7) ^ ((tid >> 3) & 7)) * 8;  // swizzled src (elems)
  const unsigned short* aSrc = xb + (size_t)(m0 + rowoff) * D_N + lsl;
  const unsigned short* bSrc = Wp + (size_t)(n0 + rowoff) * D_N + lsl;
  const int dstOff = wv * 1024;    // wave-uniform LDS dest part (+lane*16 hw)

  const int h3 = c16 & 7;

#pragma unroll 1
  for (int t = 0; t < 8; ++t) {
    const int k0 = t * 64;
#pragma unroll
    for (int i = 0; i < 4; ++i)
      GLOAD16(aSrc + (size_t)i * (32 * D_N) + k0, smem + dstOff + i * 4096);
#pragma unroll
    for (int i = 0; i < 8; ++i)
      GLOAD16(bSrc + (size_t)i * (32 * D_N) + k0,
              smem + 16384 + dstOff + i * 4096);
    __syncthreads();            // built-in vmcnt(0) drain + barrier
#pragma unroll
    for (int kh = 0; kh < 2; ++kh) {
      const int soff = ((kh * 4 + g) ^ h3) << 4;
      bf16x8 bb[8];
#pragma unroll
      for (int nt = 0; nt < 8; ++nt)
        bb[nt] = *(const bf16x8*)(smem + 16384 +
                                  (wc * 128 + nt * 16 + c16) * 128 + soff);
#pragma unroll
      for (int mt = 0; mt < 4; ++mt) {
        bf16x8 af = *(const bf16x8*)(smem +
                                     (wr * 64 + mt * 16 + c16) * 128 + soff);
#pragma unroll
        for (int nt = 0; nt < 8; ++nt)
          acc[mt][nt] = __builtin_amdgcn_mfma_f32_16x16x32_bf16(
              af, bb[nt], acc[mt][nt], 0, 0, 0);
      }
    }
    __syncthreads();
  }

  // ---- epilogue (elementwise + fused row-sums) ----
  const float* bp = (id == 0) ? bDu : (id == 1) ? bDr1 : bDr2;
  unsigned short* outp = (id == 0) ? uP : (id == 1) ? e1P : e2P;
  float* Sp = (id == 1) ? S1 : S2;
  float bias[8];
#pragma unroll
  for (int nt = 0; nt < 8; ++nt)
    bias[nt] = bp[n0 + wc * 128 + nt * 16 + c16];

#pragma unroll
  for (int mt = 0; mt < 4; ++mt)
#pragma unroll
    for (int i = 0; i < 4; ++i) {
      int row = m0 + wr * 64 + mt * 16 + g * 4 + i;
      unsigned short* op = outp + (size_t)row * H_N + n0 + wc * 128 + c16;
      if (id == 0) {
#pragma unroll
        for (int nt = 0; nt < 8; ++nt) {
          float z = acc[mt][nt][i] + bias[nt];
          float e = __expf(2.f * z);   // tanh(z) = 1 - 2/(e^{2z}+1)
          op[nt * 16] = f2h(1.f - 2.f * __builtin_amdgcn_rcpf(e + 1.f));
        }
      } else {
        float ps = 0.f;
#pragma unroll
        for (int nt = 0; nt < 8; ++nt) {
          float e = __expf(acc[mt][nt][i] + bias[nt]);
          op[nt * 16] = f2h(e);
          ps += e;
        }
        ps += __shfl_xor(ps, 1);
        ps += __shfl_xor(ps, 2);
        ps += __shfl_xor(ps, 4);
        ps += __shfl_xor(ps, 8);
        if (c16 == 0) atomicAdd(&Sp[row], ps);
      }
    }
}

// ---------------------------------------------------------------------------
// Chunked linear-recurrence scan, x2 VECTORIZED (ushort2/float2), verified
// round 18/20.  pass1 covers chunks 0..6 only (chunk 7 partials unused).
// ---------------------------------------------------------------------------
__global__ void scan_pass1(const unsigned short* __restrict__ e1P,
                           const unsigned short* __restrict__ e2P,
                           const unsigned short* __restrict__ uP,
                           const float* __restrict__ S1,
                           const float* __restrict__ S2,
                           float* __restrict__ cP,
                           float* __restrict__ cS) {
  __shared__ float ls1[64], ls2[64];
  int gt = blockIdx.x * 256 + threadIdx.x;  // 0..57343 (chunks 0..6)
  int chunk = gt >> 13;                     // 0..6
  int r = gt & 8191;
  int b = r >> 8, hp = r & 255;
  int h = hp * 2;
  int row0 = b * T_N + chunk * 64;          // block-uniform
  if (threadIdx.x < 64) ls1[threadIdx.x] = 1.f / S1[row0 + threadIdx.x];
  else if (threadIdx.x < 128) ls2[threadIdx.x - 64] = 1.f / S2[row0 + threadIdx.x - 64];
  __syncthreads();
  size_t idx = (size_t)row0 * H_N + h;
  float p0 = 1.f, s0 = 0.f, p1 = 1.f, s1 = 0.f;
#pragma unroll 4
  for (int j = 0; j < 64; ++j) {
    ushort2 v1 = *(const ushort2*)(e1P + idx);
    ushort2 v2 = *(const ushort2*)(e2P + idx);
    ushort2 vu = *(const ushort2*)(uP + idx);
    float i1 = ls1[j], i2 = ls2[j];
    float a0 = i1 * h2f(v1.x), a1 = i1 * h2f(v1.y);
    s0 = fmaf(a0, s0, i2 * h2f(v2.x) * h2f(vu.x));
    s1 = fmaf(a1, s1, i2 * h2f(v2.y) * h2f(vu.y));
    p0 *= a0;
    p1 *= a1;
    idx += H_N;
  }
  int base = chunk * 16384 + b * 512 + h;
  *(float2*)(cP + base) = (float2){p0, p1};
  *(float2*)(cS + base) = (float2){s0, s1};
}

__global__ void scan_pass3(const unsigned short* __restrict__ e1P,
                           const unsigned short* __restrict__ e2P,
                           const unsigned short* __restrict__ uP,
                           const float* __restrict__ S1,
                           const float* __restrict__ S2,
                           const float* __restrict__ cP,
                           const float* __restrict__ cS,
                           float* __restrict__ out) {
  __shared__ float ls1[64], ls2[64];
  int gt = blockIdx.x * 256 + threadIdx.x;
  int chunk = gt >> 13;
  int r = gt & 8191;
  int b = r >> 8, hp = r & 255;
  int h = hp * 2;
  int row0 = b * T_N + chunk * 64;
  if (threadIdx.x < 64) ls1[threadIdx.x] = 1.f / S1[row0 + threadIdx.x];
  else if (threadIdx.x < 128) ls2[threadIdx.x - 64] = 1.f / S2[row0 + threadIdx.x - 64];
  int rr = b * 512 + h;
  float s0 = 0.f, s1 = 0.f;
  for (int c2 = 0; c2 < chunk; ++c2) {
    float2 pp = *(const float2*)(cP + c2 * 16384 + rr);
    float2 ss = *(const float2*)(cS + c2 * 16384 + rr);
    s0 = fmaf(pp.x, s0, ss.x);
    s1 = fmaf(pp.y, s1, ss.y);
  }
  __syncthreads();
  size_t idx = (size_t)row0 * H_N + h;
#pragma unroll 4
  for (int j = 0; j < 64; ++j) {
    ushort2 v1 = *(const ushort2*)(e1P + idx);
    ushort2 v2 = *(const ushort2*)(e2P + idx);
    ushort2 vu = *(const ushort2*)(uP + idx);
    float i1 = ls1[j], i2 = ls2[j];
    float a0 = i1 * h2f(v1.x), a1 = i1 * h2f(v1.y);
    s0 = fmaf(a0, s0, i2 * h2f(v2.x) * h2f(vu.x));
    s1 = fmaf(a1, s1, i2 * h2f(v2.y) * h2f(vu.y));
    *(float2*)(out + idx) = (float2){s0, s1};
    idx += H_N;
  }
}

extern "C" void kernel_launch(void* const* d_in, const int* in_sizes, int n_in,
                              void* d_out, int out_size, void* d_ws, size_t ws_size,
                              hipStream_t stream) {
  const float* x  = (const float*)d_in[0];
  const float* W0 = (const float*)d_in[1];
  const float* W1 = (const float*)d_in[2];
  const float* W2 = (const float*)d_in[3];
  const float* b0 = (const float*)d_in[4];
  const float* b1 = (const float*)d_in[5];
  const float* b2 = (const float*)d_in[6];
  float* out = (float*)d_out;

  char* ws = (char*)d_ws;
  unsigned short* xb  = (unsigned short*)ws;                  // 16 MB  bf16 x
  unsigned short* Wt  = (unsigned short*)(ws + 16777216);     // 1.5 MB bf16 W^T x3
  unsigned short* uP  = (unsigned short*)(ws + 18350080);     // 16 MB  f16 tanh(u)
  unsigned short* e1P = (unsigned short*)(ws + 35127296);     // 16 MB  f16 exp(z1)
  unsigned short* e2P = (unsigned short*)(ws + 51904512);     // 16 MB  f16 exp(z2)
  float*          S1  = (float*)(ws + 68681728);              // 64 KB  rowsum e1
  float*          S2  = (float*)(ws + 68747264);              // 64 KB  rowsum e2
  float*          cP  = (float*)(ws + 68812800);              // 0.5 MB chunk prod
  float*          cS  = (float*)(ws + 69337088);              // 0.5 MB chunk partial
  // total 69,861,376 bytes

  prep_kernel<<<2848, 256, 0, stream>>>(x, W0, W1, W2, xb, Wt, S1);
  gemm3<<<768, 256, 0, stream>>>(xb, Wt, b0, b1, b2, uP, e1P, e2P, S1, S2);
  scan_pass1<<<224, 256, 0, stream>>>(e1P, e2P, uP, S1, S2, cP, cS);
  scan_pass3<<<256, 256, 0, stream>>>(e1P, e2P, uP, S1, S2, cP, cS, out);
}

// Round 23
// 79.876 us; speedup vs baseline: 2.9794x; 2.9794x over previous
//
#include <hip/hip_runtime.h>
#include <hip/hip_bf16.h>

#define B_N 32
#define T_N 512
#define D_N 512
#define H_N 512
#define M_N (B_N * T_N)   // 16384

typedef __attribute__((ext_vector_type(8))) short bf16x8;   // generic 16B
typedef __attribute__((ext_vector_type(4))) float f32x4;

__device__ __forceinline__ unsigned short f2bf(float f) {
  unsigned u = __float_as_uint(f);
  u += 0x7FFFu + ((u >> 16) & 1u);   // RTNE
  return (unsigned short)(u >> 16);
}
__device__ __forceinline__ unsigned short f2h(float f) {
  _Float16 h = (_Float16)f;
  return *(unsigned short*)&h;
}
__device__ __forceinline__ float h2f(unsigned short u) {
  _Float16 h = *(_Float16*)&u;
  return (float)h;
}

#define GLOAD16(g, l) __builtin_amdgcn_global_load_lds( \
    (const __attribute__((address_space(1))) void*)(g), \
    (__attribute__((address_space(3))) void*)(l), 16, 0, 0)

// ---------------------------------------------------------------------------
// prep: blocks [0,768) transpose+convert W -> Wt[id][n][k] bf16;
// blocks [768,2816) convert x f32 -> bf16; blocks [2816,2848) zero S1/S2.
// ---------------------------------------------------------------------------
__global__ void prep_kernel(const float* __restrict__ x,
                            const float* __restrict__ W0,
                            const float* __restrict__ W1,
                            const float* __restrict__ W2,
                            unsigned short* __restrict__ xb,
                            unsigned short* __restrict__ Wt,
                            float* __restrict__ S) {
  int blk = blockIdx.x;
  int tid = threadIdx.x;
  if (blk < 768) {
    __shared__ float tile[32][33];
    int id = blk >> 8;
    int t = blk & 255;
    int kr = (t >> 4) << 5;
    int nc = (t & 15) << 5;
    const float* W = (id == 0) ? W0 : (id == 1) ? W1 : W2;
    unsigned short* Wo = Wt + (size_t)id * (D_N * H_N);
    int tx = tid & 31, ty0 = tid >> 5;
    for (int ty = ty0; ty < 32; ty += 8)
      tile[ty][tx] = W[(size_t)(kr + ty) * H_N + nc + tx];
    __syncthreads();
    for (int ty = ty0; ty < 32; ty += 8)
      Wo[(size_t)(nc + ty) * D_N + kr + tx] = f2bf(tile[tx][ty]);
  } else if (blk < 2816) {
    int b = blk - 768;
    const float4* xv = (const float4*)x;
#pragma unroll
    for (int u = 0; u < 4; ++u) {
      int i = b * 1024 + u * 256 + tid;
      float4 v = xv[i];
      ushort4 o;
      o.x = f2bf(v.x); o.y = f2bf(v.y); o.z = f2bf(v.z); o.w = f2bf(v.w);
      ((ushort4*)xb)[i] = o;
    }
  } else {
    // zero S1+S2 (contiguous 128KB = 8192 float4)
    ((float4*)S)[(blk - 2816) * 256 + tid] = (float4){0.f, 0.f, 0.f, 0.f};
  }
}

// ---------------------------------------------------------------------------
// gemm3 v21 (VERIFIED 43.2us, BANKED): 256x128 tile (8 waves, 4x2 of 64x64
// quadrants), BK=64, 8 K-steps, single 48KB LDS buffer (A 32KB @0, B 16KB
// @32768), plain __syncthreads, launch_bounds(512,4) (VGPR 56 + acc 64 =
// 120 <= 128, no spill -- verified WRITE 53MB).
// Session conclusion: six structurally distinct configs (1/2/4 blocks/CU,
// 8/16 K-steps, 2x staging deltas, 64x128 tiles [spilled], A-direct
// [L2-serialized]) land at >= 43us; 43us is the structural fixed point of
// this decomposition family on gfx950 at these shapes.  v22 lesson:
// acc[4][8] (128 AGPR) exceeds the register budget -> 1GB scratch traffic.
// T1 chunked XCD swizzle (nwg=768=8*96).  LDS swizzle (v1/v7-verified,
// 128B rows): phys 16B slot = s ^ (row&7); inverse folded into per-lane
// GLOBAL source (rule 21).  Epilogue verified v10 (absmax 4.88e-4).
// ---------------------------------------------------------------------------
__global__ __launch_bounds__(512, 4) void gemm3(
    const unsigned short* __restrict__ xb,
    const unsigned short* __restrict__ Wt,
    const float* __restrict__ bDu,
    const float* __restrict__ bDr1,
    const float* __restrict__ bDr2,
    unsigned short* __restrict__ uP,
    unsigned short* __restrict__ e1P,
    unsigned short* __restrict__ e2P,
    float* __restrict__ S1,
    float* __restrict__ S2) {
  __shared__ __align__(16) char smem[49152];   // A @0 (32KB), B @32768 (16KB)

  // chunked XCD swizzle (nwg=768 = 8*96): XCD k gets wg [k*96, k*96+96)
  const int wg = (blockIdx.x & 7) * 96 + (blockIdx.x >> 3);
  const int bx = wg / 12;           // 0..63
  const int rzy = wg - bx * 12;
  const int id = rzy >> 2;          // 0..2
  const int by = rzy & 3;           // 0..3

  const int tid = threadIdx.x;      // 0..511
  const int lane = tid & 63;
  const int wv = tid >> 6;          // 0..7
  const int wr = wv >> 1;           // wave row (0..3)
  const int wc = wv & 1;            // wave col (0..1)
  const int g = lane >> 4;          // 0..3
  const int c16 = lane & 15;

  const int m0 = bx * 256;
  const int n0 = by * 128;
  const unsigned short* Wp = Wt + (size_t)id * (D_N * H_N);

  f32x4 acc[4][4];
#pragma unroll
  for (int mt = 0; mt < 4; ++mt)
#pragma unroll
    for (int nt = 0; nt < 4; ++nt)
      acc[mt][nt] = (f32x4){0.f, 0.f, 0.f, 0.f};

  // staging: chunk c -> row c>>3, phys slot c&7; logical slot = phys^(row&7).
  // A: 2048 chunks, thread does i=0..3 (row = i*64 + (tid>>3));
  // B: 1024 chunks, thread does i=0..1.
  const int rowoff = tid >> 3;                         // 0..63
  const int lsl = ((tid & 7) ^ ((tid >> 3) & 7)) * 8;  // swizzled src (elems)
  const unsigned short* aSrc = xb + (size_t)(m0 + rowoff) * D_N + lsl;
  const unsigned short* bSrc = Wp + (size_t)(n0 + rowoff) * D_N + lsl;
  const int dstOff = wv * 1024;    // wave-uniform LDS dest part (+lane*16 hw)

  const int h3 = c16 & 7;

#pragma unroll 1
  for (int t = 0; t < 8; ++t) {
    const int k0 = t * 64;
#pragma unroll
    for (int i = 0; i < 4; ++i)
      GLOAD16(aSrc + (size_t)i * (64 * D_N) + k0, smem + dstOff + i * 8192);
#pragma unroll
    for (int i = 0; i < 2; ++i)
      GLOAD16(bSrc + (size_t)i * (64 * D_N) + k0,
              smem + 32768 + dstOff + i * 8192);
    __syncthreads();            // built-in vmcnt(0) drain + barrier
#pragma unroll
    for (int kh = 0; kh < 2; ++kh) {
      const int soff = ((kh * 4 + g) ^ h3) << 4;
      bf16x8 bb[4];
#pragma unroll
      for (int nt = 0; nt < 4; ++nt)
        bb[nt] = *(const bf16x8*)(smem + 32768 +
                                  (wc * 64 + nt * 16 + c16) * 128 + soff);
#pragma unroll
      for (int mt = 0; mt < 4; ++mt) {
        bf16x8 af = *(const bf16x8*)(smem +
                                     (wr * 64 + mt * 16 + c16) * 128 + soff);
#pragma unroll
        for (int nt = 0; nt < 4; ++nt)
          acc[mt][nt] = __builtin_amdgcn_mfma_f32_16x16x32_bf16(
              af, bb[nt], acc[mt][nt], 0, 0, 0);
      }
    }
    __syncthreads();
  }

  // ---- epilogue (elementwise + fused row-sums) ----
  const float* bp = (id == 0) ? bDu : (id == 1) ? bDr1 : bDr2;
  unsigned short* outp = (id == 0) ? uP : (id == 1) ? e1P : e2P;
  float* Sp = (id == 1) ? S1 : S2;
  float bias[4];
#pragma unroll
  for (int nt = 0; nt < 4; ++nt)
    bias[nt] = bp[n0 + wc * 64 + nt * 16 + c16];

#pragma unroll
  for (int mt = 0; mt < 4; ++mt)
#pragma unroll
    for (int i = 0; i < 4; ++i) {
      int row = m0 + wr * 64 + mt * 16 + g * 4 + i;
      unsigned short* op = outp + (size_t)row * H_N + n0 + wc * 64 + c16;
      if (id == 0) {
#pragma unroll
        for (int nt = 0; nt < 4; ++nt) {
          float z = acc[mt][nt][i] + bias[nt];
          float e = __expf(2.f * z);   // tanh(z) = 1 - 2/(e^{2z}+1)
          op[nt * 16] = f2h(1.f - 2.f * __builtin_amdgcn_rcpf(e + 1.f));
        }
      } else {
        float ps = 0.f;
#pragma unroll
        for (int nt = 0; nt < 4; ++nt) {
          float e = __expf(acc[mt][nt][i] + bias[nt]);
          op[nt * 16] = f2h(e);
          ps += e;
        }
        ps += __shfl_xor(ps, 1);
        ps += __shfl_xor(ps, 2);
        ps += __shfl_xor(ps, 4);
        ps += __shfl_xor(ps, 8);
        if (c16 == 0) atomicAdd(&Sp[row], ps);
      }
    }
}

// ---------------------------------------------------------------------------
// Chunked linear-recurrence scan, x2 VECTORIZED (ushort2/float2), verified
// round 18/20/21.  pass1 covers chunks 0..6 only (chunk 7 partials unused).
// ---------------------------------------------------------------------------
__global__ void scan_pass1(const unsigned short* __restrict__ e1P,
                           const unsigned short* __restrict__ e2P,
                           const unsigned short* __restrict__ uP,
                           const float* __restrict__ S1,
                           const float* __restrict__ S2,
                           float* __restrict__ cP,
                           float* __restrict__ cS) {
  __shared__ float ls1[64], ls2[64];
  int gt = blockIdx.x * 256 + threadIdx.x;  // 0..57343 (chunks 0..6)
  int chunk = gt >> 13;                     // 0..6
  int r = gt & 8191;
  int b = r >> 8, hp = r & 255;
  int h = hp * 2;
  int row0 = b * T_N + chunk * 64;          // block-uniform
  if (threadIdx.x < 64) ls1[threadIdx.x] = 1.f / S1[row0 + threadIdx.x];
  else if (threadIdx.x < 128) ls2[threadIdx.x - 64] = 1.f / S2[row0 + threadIdx.x - 64];
  __syncthreads();
  size_t idx = (size_t)row0 * H_N + h;
  float p0 = 1.f, s0 = 0.f, p1 = 1.f, s1 = 0.f;
#pragma unroll 4
  for (int j = 0; j < 64; ++j) {
    ushort2 v1 = *(const ushort2*)(e1P + idx);
    ushort2 v2 = *(const ushort2*)(e2P + idx);
    ushort2 vu = *(const ushort2*)(uP + idx);
    float i1 = ls1[j], i2 = ls2[j];
    float a0 = i1 * h2f(v1.x), a1 = i1 * h2f(v1.y);
    s0 = fmaf(a0, s0, i2 * h2f(v2.x) * h2f(vu.x));
    s1 = fmaf(a1, s1, i2 * h2f(v2.y) * h2f(vu.y));
    p0 *= a0;
    p1 *= a1;
    idx += H_N;
  }
  int base = chunk * 16384 + b * 512 + h;
  *(float2*)(cP + base) = (float2){p0, p1};
  *(float2*)(cS + base) = (float2){s0, s1};
}

__global__ void scan_pass3(const unsigned short* __restrict__ e1P,
                           const unsigned short* __restrict__ e2P,
                           const unsigned short* __restrict__ uP,
                           const float* __restrict__ S1,
                           const float* __restrict__ S2,
                           const float* __restrict__ cP,
                           const float* __restrict__ cS,
                           float* __restrict__ out) {
  __shared__ float ls1[64], ls2[64];
  int gt = blockIdx.x * 256 + threadIdx.x;
  int chunk = gt >> 13;
  int r = gt & 8191;
  int b = r >> 8, hp = r & 255;
  int h = hp * 2;
  int row0 = b * T_N + chunk * 64;
  if (threadIdx.x < 64) ls1[threadIdx.x] = 1.f / S1[row0 + threadIdx.x];
  else if (threadIdx.x < 128) ls2[threadIdx.x - 64] = 1.f / S2[row0 + threadIdx.x - 64];
  int rr = b * 512 + h;
  float s0 = 0.f, s1 = 0.f;
  for (int c2 = 0; c2 < chunk; ++c2) {
    float2 pp = *(const float2*)(cP + c2 * 16384 + rr);
    float2 ss = *(const float2*)(cS + c2 * 16384 + rr);
    s0 = fmaf(pp.x, s0, ss.x);
    s1 = fmaf(pp.y, s1, ss.y);
  }
  __syncthreads();
  size_t idx = (size_t)row0 * H_N + h;
#pragma unroll 4
  for (int j = 0; j < 64; ++j) {
    ushort2 v1 = *(const ushort2*)(e1P + idx);
    ushort2 v2 = *(const ushort2*)(e2P + idx);
    ushort2 vu = *(const ushort2*)(uP + idx);
    float i1 = ls1[j], i2 = ls2[j];
    float a0 = i1 * h2f(v1.x), a1 = i1 * h2f(v1.y);
    s0 = fmaf(a0, s0, i2 * h2f(v2.x) * h2f(vu.x));
    s1 = fmaf(a1, s1, i2 * h2f(v2.y) * h2f(vu.y));
    *(float2*)(out + idx) = (float2){s0, s1};
    idx += H_N;
  }
}

extern "C" void kernel_launch(void* const* d_in, const int* in_sizes, int n_in,
                              void* d_out, int out_size, void* d_ws, size_t ws_size,
                              hipStream_t stream) {
  const float* x  = (const float*)d_in[0];
  const float* W0 = (const float*)d_in[1];
  const float* W1 = (const float*)d_in[2];
  const float* W2 = (const float*)d_in[3];
  const float* b0 = (const float*)d_in[4];
  const float* b1 = (const float*)d_in[5];
  const float* b2 = (const float*)d_in[6];
  float* out = (float*)d_out;

  char* ws = (char*)d_ws;
  unsigned short* xb  = (unsigned short*)ws;                  // 16 MB  bf16 x
  unsigned short* Wt  = (unsigned short*)(ws + 16777216);     // 1.5 MB bf16 W^T x3
  unsigned short* uP  = (unsigned short*)(ws + 18350080);     // 16 MB  f16 tanh(u)
  unsigned short* e1P = (unsigned short*)(ws + 35127296);     // 16 MB  f16 exp(z1)
  unsigned short* e2P = (unsigned short*)(ws + 51904512);     // 16 MB  f16 exp(z2)
  float*          S1  = (float*)(ws + 68681728);              // 64 KB  rowsum e1
  float*          S2  = (float*)(ws + 68747264);              // 64 KB  rowsum e2
  float*          cP  = (float*)(ws + 68812800);              // 0.5 MB chunk prod
  float*          cS  = (float*)(ws + 69337088);              // 0.5 MB chunk partial
  // total 69,861,376 bytes

  prep_kernel<<<2848, 256, 0, stream>>>(x, W0, W1, W2, xb, Wt, S1);
  gemm3<<<768, 512, 0, stream>>>(xb, Wt, b0, b1, b2, uP, e1P, e2P, S1, S2);
  scan_pass1<<<224, 256, 0, stream>>>(e1P, e2P, uP, S1, S2, cP, cS);
  scan_pass3<<<256, 256, 0, stream>>>(e1P, e2P, uP, S1, S2, cP, cS, out);
}